// Round 3
// baseline (256.623 us; speedup 1.0000x reference)
//
#include <hip/hip_runtime.h>
#include <cmath>

#define LBINS 401
#define LL 160801
#define MIN_SEP 2
#define PSTRIDE 405      // per-partial floats: 401 bins + HA,HC,SWm,SMm
#define UNR 8
#define NSEG 3           // i-segments per batch
#define NYB  (NSEG * 2)  // blocks per batch = segments x kgroups

// accum column layout (floats)
#define ACC_HANY  401
#define ACC_HCONV 402
#define ACC_SWM   403
#define ACC_SMM   404

// ---------------------------------------------------------------------------
// main: skewed-torus diagonal walk (lane owns diagonal k; j=(i+k) mod 401).
// Round-3 changes vs round-2 (latency-structure, not instruction mix):
//  * 6 blocks/batch (i-thirds x 2 kgroups) + __launch_bounds__(256,6):
//    exactly 6 blocks/CU resident = 24 waves/CU (was 16) for latency hiding.
//  * software-pipelined inner loop: prefetch batch n+1's global loads (and
//    LDS col words) while computing batch n -> loads stay in flight across
//    the compute phase instead of draining vmcnt every 8 elements.
//  * col masks stored as uint[401] (ds_read_b32, conflict-free) instead of
//    bytes (64 consecutive bytes = 16 banks = 4-way conflict).
// Exactness: every accumulator receives the identical value sequence as
// round-2 (wrap split via ct = wr?c:0; SMw+=ct; SMk+=c-ct which is exactly
// {0,c}); only the block partial boundaries moved (thirds vs halves), so
// cross-block reduce order shifts by ulps at most.
// ---------------------------------------------------------------------------
__global__ __launch_bounds__(256, 6)
void main_kernel(const float* __restrict__ cm,
                 const float* __restrict__ logits,
                 const int* __restrict__ ctcf,
                 float* __restrict__ parts,
                 int* __restrict__ partsI,
                 int* __restrict__ cnt) {
    int b      = blockIdx.x;
    int B      = gridDim.x;
    int y      = blockIdx.y;
    int iseg   = y >> 1;         // 0..2
    int kgroup = y & 1;          // 0..1
    int u      = threadIdx.x;
    int k      = kgroup * 256 + u;
    bool active = (k < LBINS);

    __shared__ unsigned int colu[LBINS];            // b0=any_j b1=rev_j b2=comp_j
    __shared__ __align__(8) unsigned char row8[LBINS + 7]; // b0=any_i b1=fwd_i b2=!comp_i
    __shared__ float lb[LBINS];
    __shared__ float sred[4][4];
    __shared__ int   ired[4][4];

    const int*   ct = ctcf   + (size_t)b * LBINS;
    const float* lg = logits + (size_t)b * LBINS * 2;
    for (int t = u; t < LBINS; t += 256) {
        int o = ct[t];
        unsigned any = (o != 0)  ? 1u : 0u;
        unsigned rev = (o == -1) ? 1u : 0u;
        unsigned fwd = (o == 1)  ? 1u : 0u;
        unsigned cj  = (lg[2 * t + 1] > lg[2 * t]) ? 1u : 0u;
        colu[t] = any | (rev << 1) | (cj << 2);
        row8[t] = (unsigned char)(any | (fwd << 1) | ((1u - cj) << 2));
        lb[t] = 0.f;
    }
    if (u < 7) row8[LBINS + u] = 0;
    if (b == 0 && y == 0 && u == 0)
        __hip_atomic_store(cnt, 0, __ATOMIC_RELAXED, __HIP_MEMORY_SCOPE_AGENT);
    __syncthreads();

    if (y == 0) {
        // fused prep: per-batch closed-form counts from staged col bits
        int na = 0, nr = 0, n1 = 0, adj = 0;
        for (int t = u; t < LBINS; t += 256) {
            unsigned cb = colu[t];
            na += (int)(cb & 1u);
            nr += (int)((cb >> 1) & 1u);
            n1 += (int)((cb >> 2) & 1u);
            if (t >= 1) adj += (int)((((cb ^ colu[t - 1]) >> 2) & 1u) ^ 1u);
        }
        #pragma unroll
        for (int off = 32; off > 0; off >>= 1) {
            na  += __shfl_down(na,  off, 64);
            nr  += __shfl_down(nr,  off, 64);
            n1  += __shfl_down(n1,  off, 64);
            adj += __shfl_down(adj, off, 64);
        }
        int w = u >> 6;
        if ((u & 63) == 0) {
            ired[w][0] = na; ired[w][1] = nr; ired[w][2] = n1; ired[w][3] = adj;
        }
        __syncthreads();
        if (u == 0) {
            int NA = ired[0][0] + ired[1][0] + ired[2][0] + ired[3][0];
            int NR = ired[0][1] + ired[1][1] + ired[2][1] + ired[3][1];
            int N1 = ired[0][2] + ired[1][2] + ired[2][2] + ired[3][2];
            int AD = ired[0][3] + ired[1][3] + ired[2][3] + ired[3][3];
            int NF = NA - NR;
            int N0 = LBINS - N1;
            partsI[b]     = NA * NA - NF * NR;                   // nc per batch
            partsI[B + b] = N0 * N0 + N1 * N1 - LBINS - 2 * AD;  // same per batch
        }
    }

    int i0 = (iseg == 0) ? 0   : (iseg == 1) ? 134 : 268;
    int ie = (iseg == 0) ? 134 : (iseg == 1) ? 268 : 401;

    const float* cmb = cm + (size_t)b * LL;
    float HA = 0.f, HC = 0.f;
    float SMk = 0.f, SMw = 0.f, SWk = 0.f, SWw = 0.f;

    if (active) {
        int wthr = LBINS - k;    // i >= wthr  <=>  wrapped

// one element, identical math to round-2 (value-exact)
#define STEP1(II)                                                          \
    do {                                                                   \
        int ii_ = (II);                                                    \
        int j_ = ii_ + k;                                                  \
        bool wr_ = (j_ >= LBINS);                                          \
        int jc_ = wr_ ? j_ - LBINS : j_;                                   \
        float c_ = cmb[(unsigned)(ii_ * LBINS + jc_)];                     \
        unsigned cbq_ = colu[jc_];                                         \
        unsigned rbq_ = row8[ii_];                                         \
        float rc_ = fmaxf(c_, 0.f);                                        \
        unsigned bnd_ = rbq_ & cbq_;                                       \
        int m0_ = (int)(bnd_ << 31) >> 31;                                 \
        int m1_ = (int)(bnd_ << 30) >> 31;                                 \
        int ms_ = (int)((rbq_ ^ cbq_) << 29) >> 31;                        \
        HA += __int_as_float(__float_as_int(rc_) & m0_);                   \
        HC += __int_as_float(__float_as_int(rc_) & m1_);                   \
        float cs_ = __int_as_float(__float_as_int(c_) & ms_);              \
        float ct_  = wr_ ? c_  : 0.f;                                      \
        float cst_ = wr_ ? cs_ : 0.f;                                      \
        SMw += ct_;  SMk += (c_ - ct_);                                    \
        SWw += cst_; SWk += (cs_ - cst_);                                  \
    } while (0)

// prefetch a full batch: 8 global loads + 8 LDS col words + row window
#define PRE(IB, CV, CB, RW)                                                \
    do {                                                                   \
        int ib_ = (IB);                                                    \
        RW = *(const unsigned long long*)(row8 + ib_);                     \
        _Pragma("unroll")                                                  \
        for (int q = 0; q < UNR; ++q) {                                    \
            int ii_ = ib_ + q;                                             \
            int j_ = ii_ + k;                                              \
            int jc_ = (j_ >= LBINS) ? j_ - LBINS : j_;                     \
            CV[q] = cmb[(unsigned)(ii_ * LBINS + jc_)];                    \
            CB[q] = colu[jc_];                                             \
        }                                                                  \
    } while (0)

// compute a prefetched batch (wrap recomputed from wthr: 2 insts, no regs)
#define CMP(IB, CV, CB, RW)                                                \
    do {                                                                   \
        int ib_ = (IB);                                                    \
        _Pragma("unroll")                                                  \
        for (int q = 0; q < UNR; ++q) {                                    \
            unsigned cbq_ = CB[q];                                         \
            unsigned rbq_ = (unsigned)((RW) >> (8 * q)) & 0xffu;           \
            float c_ = CV[q];                                              \
            bool wr_ = (ib_ + q) >= wthr;                                  \
            float rc_ = fmaxf(c_, 0.f);                                    \
            unsigned bnd_ = rbq_ & cbq_;                                   \
            int m0_ = (int)(bnd_ << 31) >> 31;                             \
            int m1_ = (int)(bnd_ << 30) >> 31;                             \
            int ms_ = (int)((rbq_ ^ cbq_) << 29) >> 31;                    \
            HA += __int_as_float(__float_as_int(rc_) & m0_);               \
            HC += __int_as_float(__float_as_int(rc_) & m1_);               \
            float cs_ = __int_as_float(__float_as_int(c_) & ms_);          \
            float ct_  = wr_ ? c_  : 0.f;                                  \
            float cst_ = wr_ ? cs_ : 0.f;                                  \
            SMw += ct_;  SMk += (c_ - ct_);                                \
            SWw += cst_; SWk += (cs_ - cst_);                              \
        }                                                                  \
    } while (0)

        int i  = i0;
        int iu = i0 + ((8 - (i0 & 7)) & 7);      // first 8-aligned i
        if (iu > ie) iu = ie;
        for (; i < iu; ++i) STEP1(i);            // prologue

        int nb = (ie - i) >> 3;                  // full 8-batches remaining
        if (nb > 0) {
            float cvA[UNR], cvB[UNR];
            unsigned cbA[UNR], cbB[UNR];
            unsigned long long rwA, rwB;
            int ibA = i, ibB;

            PRE(ibA, cvA, cbA, rwA);
            i += 8; --nb;
            while (nb >= 2) {                    // 2-phase pipelined steady state
                ibB = i; PRE(ibB, cvB, cbB, rwB);
                CMP(ibA, cvA, cbA, rwA);
                i += 8;
                ibA = i; PRE(ibA, cvA, cbA, rwA);
                CMP(ibB, cvB, cbB, rwB);
                i += 8;
                nb -= 2;
            }
            if (nb == 1) {
                ibB = i; PRE(ibB, cvB, cbB, rwB);
                CMP(ibA, cvA, cbA, rwA);
                i += 8;
                CMP(ibB, cvB, cbB, rwB);
            } else {
                CMP(ibA, cvA, cbA, rwA);
            }
        }
        for (; i < ie; ++i) STEP1(i);            // tail
#undef STEP1
#undef PRE
#undef CMP
    }

    // per-lane epilogue: bins via register sums (two per lane)
    float SWm = 0.f, SMm = 0.f;
    if (active) {
        int dw = LBINS - k;               // d of wrapped part (k>0)
        atomicAdd(&lb[k], SMk);
        if (k > 0) atomicAdd(&lb[dw], SMw);
        float mk = (k  >= MIN_SEP) ? 1.f : 0.f;
        float mw = (dw >= MIN_SEP) ? 1.f : 0.f;
        SWm = SWk * mk + SWw * mw;
        SMm = SMk * mk + SMw * mw;
    }

    #pragma unroll
    for (int off = 32; off > 0; off >>= 1) {
        HA  += __shfl_down(HA,  off, 64);
        HC  += __shfl_down(HC,  off, 64);
        SWm += __shfl_down(SWm, off, 64);
        SMm += __shfl_down(SMm, off, 64);
    }
    int w = u >> 6;
    if ((u & 63) == 0) {
        sred[w][0] = HA; sred[w][1] = HC; sred[w][2] = SWm; sred[w][3] = SMm;
    }
    __syncthreads();

    float* pout = parts + (size_t)(y * gridDim.x + b) * PSTRIDE;
    for (int t = u; t < LBINS; t += 256) pout[t] = lb[t];
    if (u == 0) {
        float a = 0.f, c2 = 0.f, s = 0.f, m = 0.f;
        #pragma unroll
        for (int q = 0; q < 4; ++q) {
            a += sred[q][0]; c2 += sred[q][1]; s += sred[q][2]; m += sred[q][3];
        }
        pout[ACC_HANY] = a; pout[ACC_HCONV] = c2;
        pout[ACC_SWM]  = s; pout[ACC_SMM]   = m;
    }
}

// ---------------------------------------------------------------------------
// reduce + fused final (unchanged from round-2 except npart = 6B).
// ---------------------------------------------------------------------------
__device__ double br256(double v, double* buf) {
    int tid = threadIdx.x;
    buf[tid] = v;
    __syncthreads();
    for (int off = 128; off > 0; off >>= 1) {
        if (tid < off) buf[tid] += buf[tid + off];
        __syncthreads();
    }
    double r = buf[0];
    __syncthreads();
    return r;
}

__global__ __launch_bounds__(256)
void reduce_final_kernel(const float* __restrict__ parts,
                         const int* __restrict__ partsI,
                         float* __restrict__ accum,
                         int* __restrict__ accumI,
                         int* __restrict__ cnt,
                         float* __restrict__ out,
                         int B) {
    int s = blockIdx.x;              // 0..406
    int u = threadIdx.x;
    int npart = NYB * B;
    __shared__ float r4[4];
    __shared__ int   ri4[4];
    __shared__ int   lastFlag;

    if (s < PSTRIDE) {
        float acc = 0.f;
        for (int p = u; p < npart; p += 256) acc += parts[(size_t)p * PSTRIDE + s];
        #pragma unroll
        for (int off = 32; off > 0; off >>= 1) acc += __shfl_down(acc, off, 64);
        if ((u & 63) == 0) r4[u >> 6] = acc;
        __syncthreads();
        if (u == 0)
            __hip_atomic_store(&accum[s], r4[0] + r4[1] + r4[2] + r4[3],
                               __ATOMIC_RELAXED, __HIP_MEMORY_SCOPE_AGENT);
    } else {
        int col = s - PSTRIDE;       // 0: nc_sum, 1: same_cnt (exact ints)
        int acc = 0;
        for (int p = u; p < B; p += 256) acc += partsI[col * B + p];
        #pragma unroll
        for (int off = 32; off > 0; off >>= 1) acc += __shfl_down(acc, off, 64);
        if ((u & 63) == 0) ri4[u >> 6] = acc;
        __syncthreads();
        if (u == 0)
            __hip_atomic_store(&accumI[col], ri4[0] + ri4[1] + ri4[2] + ri4[3],
                               __ATOMIC_RELAXED, __HIP_MEMORY_SCOPE_AGENT);
    }

    if (u == 0) {
        int prev = __hip_atomic_fetch_add(cnt, 1, __ATOMIC_ACQ_REL,
                                          __HIP_MEMORY_SCOPE_AGENT);
        lastFlag = (prev == (int)gridDim.x - 1);
    }
    __syncthreads();
    if (!lastFlag) return;

    // ---- final (runs in whichever block finished last) ----
    __shared__ double dred[256];

    double nc_sum   = (double)__hip_atomic_load(&accumI[0], __ATOMIC_RELAXED,
                                                __HIP_MEMORY_SCOPE_AGENT);
    double same_cnt = (double)__hip_atomic_load(&accumI[1], __ATOMIC_RELAXED,
                                                __HIP_MEMORY_SCOPE_AGENT);
    double total_maskf = (double)B * ((double)LL - 3.0 * LBINS + 2.0);
    double diff_cnt = total_maskf - same_cnt;

    float w0 = 0.f, x0 = 0.f, y0 = 0.f;
    float w1 = 0.f, x1 = 0.f, y1 = 0.f;
    {
        int t0 = u;                  // always < LBINS
        float a0 = __hip_atomic_load(&accum[t0], __ATOMIC_RELAXED,
                                     __HIP_MEMORY_SCOPE_AGENT);
        float cntB = ((t0 == 0) ? (float)LBINS : 2.0f * (float)(LBINS - t0)) * (float)B;
        float mc = a0 / cntB;
        int valid = (t0 >= MIN_SEP) && __builtin_isfinite(mc) && (mc > 0.0f);
        w0 = valid ? 1.f : 0.f;
        x0 = logf(fmaxf((float)t0, 1.0f));
        y0 = logf((valid ? mc : 1.0f) + 1e-6f);
    }
    int t1 = u + 256;
    if (t1 < LBINS) {
        float a1 = __hip_atomic_load(&accum[t1], __ATOMIC_RELAXED,
                                     __HIP_MEMORY_SCOPE_AGENT);
        float cntB = 2.0f * (float)(LBINS - t1) * (float)B;
        float mc = a1 / cntB;
        int valid = __builtin_isfinite(mc) && (mc > 0.0f);   // t1 >= MIN_SEP always
        w1 = valid ? 1.f : 0.f;
        x1 = logf((float)t1);
        y1 = logf((valid ? mc : 1.0f) + 1e-6f);
    }
    double n  = br256((double)w0 + (double)w1, dred);
    double Sx = br256((double)(w0 * x0) + (double)(w1 * x1), dred);
    double Sy = br256((double)(w0 * y0) + (double)(w1 * y1), dred);
    double n_safe = fmax(n, 1.0);
    double xm = Sx / n_safe, ym = Sy / n_safe;
    double num = br256((double)w0 * ((double)x0 - xm) * ((double)y0 - ym)
                     + (double)w1 * ((double)x1 - xm) * ((double)y1 - ym), dred);
    double den = br256((double)w0 * ((double)x0 - xm) * ((double)x0 - xm)
                     + (double)w1 * ((double)x1 - xm) * ((double)x1 - xm), dred);

    if (u == 0) {
        double slope = num / (den + 1e-8);
        float dist_loss = (n >= 5.0) ? (float)((slope + 0.85) * (slope + 0.85)) : 0.0f;

        float fHA = __hip_atomic_load(&accum[ACC_HANY],  __ATOMIC_RELAXED, __HIP_MEMORY_SCOPE_AGENT);
        float fHC = __hip_atomic_load(&accum[ACC_HCONV], __ATOMIC_RELAXED, __HIP_MEMORY_SCOPE_AGENT);
        float fSW = __hip_atomic_load(&accum[ACC_SWM],   __ATOMIC_RELAXED, __HIP_MEMORY_SCOPE_AGENT);
        float fSM = __hip_atomic_load(&accum[ACC_SMM],   __ATOMIC_RELAXED, __HIP_MEMORY_SCOPE_AGENT);

        float ncf = (float)nc_sum;
        float hinge = (fHA - fHC) / (ncf + 1e-6f);
        float ctcf_loss = (ncf < 1.0f) ? 0.0f : hinge;

        float within  = fSW / (float)fmax(same_cnt, 1.0);
        float between = (fSM - fSW) / (float)fmax(diff_cnt, 1.0);
        float ratio = within / (fabsf(between) + 1e-6f);
        float comp_loss = fmaxf(1.5f - ratio, 0.0f);

        float total = 1.0f * dist_loss + 0.5f * ctcf_loss + 0.5f * comp_loss;
        out[0] = dist_loss;
        out[1] = ctcf_loss;
        out[2] = comp_loss;
        out[3] = total;
    }
}

// ---------------------------------------------------------------------------
extern "C" void kernel_launch(void* const* d_in, const int* in_sizes, int n_in,
                              void* d_out, int out_size, void* d_ws, size_t ws_size,
                              hipStream_t stream) {
    const float* cm     = (const float*)d_in[0];   // (B, L, L) fp32
    const float* logits = (const float*)d_in[1];   // (B, L, 2) fp32
    const int*   ctcf   = (const int*)d_in[2];     // (B, L) int32
    float* out = (float*)d_out;

    int total = in_sizes[0];
    int B = total / LL;

    float* wsf    = (float*)d_ws;
    float* accum  = wsf;                        // 405 floats
    int*   accumI = (int*)(wsf + 408);          // 2 ints (nc_sum, same_cnt)
    int*   cnt    = (int*)(wsf + 412);          // finish counter
    int*   partsI = (int*)(wsf + 416);          // 2*B ints (per-batch counts)
    int parts_off = (416 + 2 * B + 255) & ~255;
    float* parts  = wsf + parts_off;            // NYB*B * PSTRIDE floats

    main_kernel<<<dim3(B, NYB), 256, 0, stream>>>(cm, logits, ctcf, parts, partsI, cnt);
    reduce_final_kernel<<<PSTRIDE + 2, 256, 0, stream>>>(parts, partsI, accum,
                                                         accumI, cnt, out, B);
}

// Round 4
// 255.561 us; speedup vs baseline: 1.0042x; 1.0042x over previous
//
#include <hip/hip_runtime.h>
#include <cmath>

#define LBINS 401
#define LL 160801
#define MIN_SEP 2
#define PSTRIDE 405      // per-partial floats: 401 bins + HA,HC,SWm,SMm
#define UNR 8
#define NSEG 3           // i-segments per batch (blocks per batch)
#define BLK 512          // threads per block (8 waves; lanes 0..400 own diagonals)

// accum column layout (floats)
#define ACC_HANY  401
#define ACC_HCONV 402
#define ACC_SWM   403
#define ACC_SMM   404

// ---------------------------------------------------------------------------
// main: skewed-torus diagonal walk, SLAB-CONTIGUOUS blocks.
// Round-4 change vs round-3 (address-stream, not instruction mix):
//   512-thread blocks, single k-group: lane u owns diagonal k=u (u<401).
//   Per row ii the block's waves read the ENTIRE row (rotated dense window),
//   so each block streams one contiguous ~215 KB slab of cm front-to-back
//   (12.8 KB per 8-row unroll window) -> high DRAM page-hit rate, vs the
//   previous 256/580-B chunks at 1608-B stride (page-miss per request).
//   Grid (B, 3) = 768 blocks = exactly 3/CU at launch_bounds(512,6).
// Per-lane element math is identical to round-2/3 (value-exact); only the
// block grouping of partials changes (same class as r3's halves->thirds).
// ---------------------------------------------------------------------------
__global__ __launch_bounds__(BLK, 6)
void main_kernel(const float* __restrict__ cm,
                 const float* __restrict__ logits,
                 const int* __restrict__ ctcf,
                 float* __restrict__ parts,
                 int* __restrict__ partsI,
                 int* __restrict__ cnt) {
    int b    = blockIdx.x;
    int B    = gridDim.x;
    int iseg = blockIdx.y;       // 0..2
    int u    = threadIdx.x;
    int k    = u;
    bool active = (k < LBINS);

    __shared__ unsigned int colu[LBINS];            // b0=any_j b1=rev_j b2=comp_j
    __shared__ __align__(8) unsigned char row8[LBINS + 7]; // b0=any_i b1=fwd_i b2=!comp_i
    __shared__ float lb[LBINS];
    __shared__ float sred[8][4];
    __shared__ int   ired[8][4];

    const int*   ct = ctcf   + (size_t)b * LBINS;
    const float* lg = logits + (size_t)b * LBINS * 2;
    for (int t = u; t < LBINS; t += BLK) {
        int o = ct[t];
        unsigned any = (o != 0)  ? 1u : 0u;
        unsigned rev = (o == -1) ? 1u : 0u;
        unsigned fwd = (o == 1)  ? 1u : 0u;
        unsigned cj  = (lg[2 * t + 1] > lg[2 * t]) ? 1u : 0u;
        colu[t] = any | (rev << 1) | (cj << 2);
        row8[t] = (unsigned char)(any | (fwd << 1) | ((1u - cj) << 2));
        lb[t] = 0.f;
    }
    if (u < 7) row8[LBINS + u] = 0;
    if (b == 0 && iseg == 0 && u == 0)
        __hip_atomic_store(cnt, 0, __ATOMIC_RELAXED, __HIP_MEMORY_SCOPE_AGENT);
    __syncthreads();

    if (iseg == 0) {
        // fused prep: per-batch closed-form counts from staged col bits
        int na = 0, nr = 0, n1 = 0, adj = 0;
        for (int t = u; t < LBINS; t += BLK) {
            unsigned cb = colu[t];
            na += (int)(cb & 1u);
            nr += (int)((cb >> 1) & 1u);
            n1 += (int)((cb >> 2) & 1u);
            if (t >= 1) adj += (int)((((cb ^ colu[t - 1]) >> 2) & 1u) ^ 1u);
        }
        #pragma unroll
        for (int off = 32; off > 0; off >>= 1) {
            na  += __shfl_down(na,  off, 64);
            nr  += __shfl_down(nr,  off, 64);
            n1  += __shfl_down(n1,  off, 64);
            adj += __shfl_down(adj, off, 64);
        }
        int w = u >> 6;
        if ((u & 63) == 0) {
            ired[w][0] = na; ired[w][1] = nr; ired[w][2] = n1; ired[w][3] = adj;
        }
        __syncthreads();
        if (u == 0) {
            int NA = 0, NR = 0, N1 = 0, AD = 0;
            #pragma unroll
            for (int q = 0; q < 8; ++q) {
                NA += ired[q][0]; NR += ired[q][1];
                N1 += ired[q][2]; AD += ired[q][3];
            }
            int NF = NA - NR;
            int N0 = LBINS - N1;
            partsI[b]     = NA * NA - NF * NR;                   // nc per batch
            partsI[B + b] = N0 * N0 + N1 * N1 - LBINS - 2 * AD;  // same per batch
        }
    }

    int i0 = (iseg == 0) ? 0   : (iseg == 1) ? 134 : 268;
    int ie = (iseg == 0) ? 134 : (iseg == 1) ? 268 : 401;

    const float* cmb = cm + (size_t)b * LL;
    float HA = 0.f, HC = 0.f;
    float SMk = 0.f, SMw = 0.f, SWk = 0.f, SWw = 0.f;

    if (active) {
        auto scalar_step = [&](int ii) {
            int j = ii + k;
            bool wr = (j >= LBINS);
            int jc = wr ? j - LBINS : j;
            float c = cmb[(unsigned)(ii * LBINS + jc)];
            unsigned cbq = colu[jc];
            unsigned rbq = row8[ii];
            float rc = fmaxf(c, 0.f);
            unsigned bnd = rbq & cbq;
            int m0 = (int)(bnd << 31) >> 31;             // any_i & any_j
            int m1 = (int)(bnd << 30) >> 31;             // fwd_i & rev_j
            int ms = (int)((rbq ^ cbq) << 29) >> 31;     // comp_i == comp_j
            HA += __int_as_float(__float_as_int(rc) & m0);
            HC += __int_as_float(__float_as_int(rc) & m1);
            float cs = __int_as_float(__float_as_int(c) & ms);
            float ctv = wr ? c  : 0.f;
            float cst = wr ? cs : 0.f;
            SMw += ctv;  SMk += (c - ctv);
            SWw += cst;  SWk += (cs - cst);
        };

        int i  = i0;
        int iu = i0 + ((8 - (i0 & 7)) & 7);      // first 8-aligned i
        if (iu > ie) iu = ie;
        for (; i < iu; ++i) scalar_step(i);      // prologue
        for (; i + UNR <= ie; i += UNR) {
            // 8 row-bit bytes in one uniform (broadcast) ds_read_b64
            unsigned long long rwin = *(const unsigned long long*)(row8 + i);
            float    cv[UNR];
            unsigned cb[UNR];
            int      wrv[UNR];
            #pragma unroll
            for (int q = 0; q < UNR; ++q) {
                int ii = i + q;
                int j  = ii + k;
                int wr = (j >= LBINS);
                int jc = wr ? j - LBINS : j;
                cv[q]  = cmb[(unsigned)(ii * LBINS + jc)];
                cb[q]  = colu[jc];
                wrv[q] = wr;
            }
            #pragma unroll
            for (int q = 0; q < UNR; ++q) {
                unsigned rbq = (unsigned)(rwin >> (8 * q)) & 0xffu;
                float c  = cv[q];
                float rc = fmaxf(c, 0.f);
                unsigned bnd = rbq & cb[q];
                int m0 = (int)(bnd << 31) >> 31;
                int m1 = (int)(bnd << 30) >> 31;
                int ms = (int)((rbq ^ cb[q]) << 29) >> 31;
                HA += __int_as_float(__float_as_int(rc) & m0);
                HC += __int_as_float(__float_as_int(rc) & m1);
                float cs = __int_as_float(__float_as_int(c) & ms);
                float ctv = wrv[q] ? c  : 0.f;
                float cst = wrv[q] ? cs : 0.f;
                SMw += ctv;  SMk += (c - ctv);
                SWw += cst;  SWk += (cs - cst);
            }
        }
        for (; i < ie; ++i) scalar_step(i);      // tail
    }

    // per-lane epilogue: bins via register sums (two per lane)
    float SWm = 0.f, SMm = 0.f;
    if (active) {
        int dw = LBINS - k;               // d of wrapped part (k>0)
        atomicAdd(&lb[k], SMk);
        if (k > 0) atomicAdd(&lb[dw], SMw);
        float mk = (k  >= MIN_SEP) ? 1.f : 0.f;
        float mw = (dw >= MIN_SEP) ? 1.f : 0.f;
        SWm = SWk * mk + SWw * mw;
        SMm = SMk * mk + SMw * mw;
    }

    #pragma unroll
    for (int off = 32; off > 0; off >>= 1) {
        HA  += __shfl_down(HA,  off, 64);
        HC  += __shfl_down(HC,  off, 64);
        SWm += __shfl_down(SWm, off, 64);
        SMm += __shfl_down(SMm, off, 64);
    }
    int w = u >> 6;
    if ((u & 63) == 0) {
        sred[w][0] = HA; sred[w][1] = HC; sred[w][2] = SWm; sred[w][3] = SMm;
    }
    __syncthreads();

    float* pout = parts + (size_t)(iseg * gridDim.x + b) * PSTRIDE;
    for (int t = u; t < LBINS; t += BLK) pout[t] = lb[t];
    if (u == 0) {
        float a = 0.f, c2 = 0.f, s = 0.f, m = 0.f;
        #pragma unroll
        for (int q = 0; q < 8; ++q) {
            a += sred[q][0]; c2 += sred[q][1]; s += sred[q][2]; m += sred[q][3];
        }
        pout[ACC_HANY] = a; pout[ACC_HCONV] = c2;
        pout[ACC_SWM]  = s; pout[ACC_SMM]   = m;
    }
}

// ---------------------------------------------------------------------------
// reduce + fused final (unchanged except npart = NSEG*B = 768).
// ---------------------------------------------------------------------------
__device__ double br256(double v, double* buf) {
    int tid = threadIdx.x;
    buf[tid] = v;
    __syncthreads();
    for (int off = 128; off > 0; off >>= 1) {
        if (tid < off) buf[tid] += buf[tid + off];
        __syncthreads();
    }
    double r = buf[0];
    __syncthreads();
    return r;
}

__global__ __launch_bounds__(256)
void reduce_final_kernel(const float* __restrict__ parts,
                         const int* __restrict__ partsI,
                         float* __restrict__ accum,
                         int* __restrict__ accumI,
                         int* __restrict__ cnt,
                         float* __restrict__ out,
                         int B) {
    int s = blockIdx.x;              // 0..406
    int u = threadIdx.x;
    int npart = NSEG * B;
    __shared__ float r4[4];
    __shared__ int   ri4[4];
    __shared__ int   lastFlag;

    if (s < PSTRIDE) {
        float acc = 0.f;
        for (int p = u; p < npart; p += 256) acc += parts[(size_t)p * PSTRIDE + s];
        #pragma unroll
        for (int off = 32; off > 0; off >>= 1) acc += __shfl_down(acc, off, 64);
        if ((u & 63) == 0) r4[u >> 6] = acc;
        __syncthreads();
        if (u == 0)
            __hip_atomic_store(&accum[s], r4[0] + r4[1] + r4[2] + r4[3],
                               __ATOMIC_RELAXED, __HIP_MEMORY_SCOPE_AGENT);
    } else {
        int col = s - PSTRIDE;       // 0: nc_sum, 1: same_cnt (exact ints)
        int acc = 0;
        for (int p = u; p < B; p += 256) acc += partsI[col * B + p];
        #pragma unroll
        for (int off = 32; off > 0; off >>= 1) acc += __shfl_down(acc, off, 64);
        if ((u & 63) == 0) ri4[u >> 6] = acc;
        __syncthreads();
        if (u == 0)
            __hip_atomic_store(&accumI[col], ri4[0] + ri4[1] + ri4[2] + ri4[3],
                               __ATOMIC_RELAXED, __HIP_MEMORY_SCOPE_AGENT);
    }

    if (u == 0) {
        int prev = __hip_atomic_fetch_add(cnt, 1, __ATOMIC_ACQ_REL,
                                          __HIP_MEMORY_SCOPE_AGENT);
        lastFlag = (prev == (int)gridDim.x - 1);
    }
    __syncthreads();
    if (!lastFlag) return;

    // ---- final (runs in whichever block finished last) ----
    __shared__ double dred[256];

    double nc_sum   = (double)__hip_atomic_load(&accumI[0], __ATOMIC_RELAXED,
                                                __HIP_MEMORY_SCOPE_AGENT);
    double same_cnt = (double)__hip_atomic_load(&accumI[1], __ATOMIC_RELAXED,
                                                __HIP_MEMORY_SCOPE_AGENT);
    double total_maskf = (double)B * ((double)LL - 3.0 * LBINS + 2.0);
    double diff_cnt = total_maskf - same_cnt;

    float w0 = 0.f, x0 = 0.f, y0 = 0.f;
    float w1 = 0.f, x1 = 0.f, y1 = 0.f;
    {
        int t0 = u;                  // always < LBINS
        float a0 = __hip_atomic_load(&accum[t0], __ATOMIC_RELAXED,
                                     __HIP_MEMORY_SCOPE_AGENT);
        float cntB = ((t0 == 0) ? (float)LBINS : 2.0f * (float)(LBINS - t0)) * (float)B;
        float mc = a0 / cntB;
        int valid = (t0 >= MIN_SEP) && __builtin_isfinite(mc) && (mc > 0.0f);
        w0 = valid ? 1.f : 0.f;
        x0 = logf(fmaxf((float)t0, 1.0f));
        y0 = logf((valid ? mc : 1.0f) + 1e-6f);
    }
    int t1 = u + 256;
    if (t1 < LBINS) {
        float a1 = __hip_atomic_load(&accum[t1], __ATOMIC_RELAXED,
                                     __HIP_MEMORY_SCOPE_AGENT);
        float cntB = 2.0f * (float)(LBINS - t1) * (float)B;
        float mc = a1 / cntB;
        int valid = __builtin_isfinite(mc) && (mc > 0.0f);   // t1 >= MIN_SEP always
        w1 = valid ? 1.f : 0.f;
        x1 = logf((float)t1);
        y1 = logf((valid ? mc : 1.0f) + 1e-6f);
    }
    double n  = br256((double)w0 + (double)w1, dred);
    double Sx = br256((double)(w0 * x0) + (double)(w1 * x1), dred);
    double Sy = br256((double)(w0 * y0) + (double)(w1 * y1), dred);
    double n_safe = fmax(n, 1.0);
    double xm = Sx / n_safe, ym = Sy / n_safe;
    double num = br256((double)w0 * ((double)x0 - xm) * ((double)y0 - ym)
                     + (double)w1 * ((double)x1 - xm) * ((double)y1 - ym), dred);
    double den = br256((double)w0 * ((double)x0 - xm) * ((double)x0 - xm)
                     + (double)w1 * ((double)x1 - xm) * ((double)x1 - xm), dred);

    if (u == 0) {
        double slope = num / (den + 1e-8);
        float dist_loss = (n >= 5.0) ? (float)((slope + 0.85) * (slope + 0.85)) : 0.0f;

        float fHA = __hip_atomic_load(&accum[ACC_HANY],  __ATOMIC_RELAXED, __HIP_MEMORY_SCOPE_AGENT);
        float fHC = __hip_atomic_load(&accum[ACC_HCONV], __ATOMIC_RELAXED, __HIP_MEMORY_SCOPE_AGENT);
        float fSW = __hip_atomic_load(&accum[ACC_SWM],   __ATOMIC_RELAXED, __HIP_MEMORY_SCOPE_AGENT);
        float fSM = __hip_atomic_load(&accum[ACC_SMM],   __ATOMIC_RELAXED, __HIP_MEMORY_SCOPE_AGENT);

        float ncf = (float)nc_sum;
        float hinge = (fHA - fHC) / (ncf + 1e-6f);
        float ctcf_loss = (ncf < 1.0f) ? 0.0f : hinge;

        float within  = fSW / (float)fmax(same_cnt, 1.0);
        float between = (fSM - fSW) / (float)fmax(diff_cnt, 1.0);
        float ratio = within / (fabsf(between) + 1e-6f);
        float comp_loss = fmaxf(1.5f - ratio, 0.0f);

        float total = 1.0f * dist_loss + 0.5f * ctcf_loss + 0.5f * comp_loss;
        out[0] = dist_loss;
        out[1] = ctcf_loss;
        out[2] = comp_loss;
        out[3] = total;
    }
}

// ---------------------------------------------------------------------------
extern "C" void kernel_launch(void* const* d_in, const int* in_sizes, int n_in,
                              void* d_out, int out_size, void* d_ws, size_t ws_size,
                              hipStream_t stream) {
    const float* cm     = (const float*)d_in[0];   // (B, L, L) fp32
    const float* logits = (const float*)d_in[1];   // (B, L, 2) fp32
    const int*   ctcf   = (const int*)d_in[2];     // (B, L) int32
    float* out = (float*)d_out;

    int total = in_sizes[0];
    int B = total / LL;

    float* wsf    = (float*)d_ws;
    float* accum  = wsf;                        // 405 floats
    int*   accumI = (int*)(wsf + 408);          // 2 ints (nc_sum, same_cnt)
    int*   cnt    = (int*)(wsf + 412);          // finish counter
    int*   partsI = (int*)(wsf + 416);          // 2*B ints (per-batch counts)
    int parts_off = (416 + 2 * B + 255) & ~255;
    float* parts  = wsf + parts_off;            // NSEG*B * PSTRIDE floats

    main_kernel<<<dim3(B, NSEG), BLK, 0, stream>>>(cm, logits, ctcf, parts, partsI, cnt);
    reduce_final_kernel<<<PSTRIDE + 2, 256, 0, stream>>>(parts, partsI, accum,
                                                         accumI, cnt, out, B);
}